// Round 5
// baseline (438.162 us; speedup 1.0000x reference)
//
#include <hip/hip_runtime.h>

#define N_POINTS 500000
#define K_CENT   512
#define W_DIM    64
#define N_JOBS   ((N_POINTS + 63) / 64)   // 7813 (last job: tile1 invalid)
#define SCALE_LO 2048.0f                  // 2^11
#define INV_LO   (1.0f / 2048.0f)

typedef _Float16 half8 __attribute__((ext_vector_type(8)));
typedef float    f32x16 __attribute__((ext_vector_type(16)));

// ---- pre-kernel 1: codebook -> fragment-ordered f16 hi/lo planes of w = -2*c.
// Layout: [t:16][plane:2][s:4][lane:64][j:8] -> 8 KB/chunk, 128 KB total.
// A-fragment mapping (mfma_f32_32x32x16_f16, verified R2): lane l holds
// row=l&31, k=(l>>5)*8+j of K-step s  => centroid c = t*32+(l&31),
// dim d = s*16 + (l>>5)*8 + j.
__global__ void cvt_kernel(const float* __restrict__ cb,
                           _Float16* __restrict__ cbf) {
    int id = blockIdx.x * 256 + threadIdx.x;           // 4096 ids
    if (id >= K_CENT * 8) return;
    int c = id >> 3, o = (id & 7) * 8;                 // centroid, dim base
    int t = c >> 5, r = c & 31;
    int s = o >> 4, half = (o >> 3) & 1;
    int lane = half * 32 + r;
    const float* src = cb + (size_t)c * W_DIM + o;
    half8 h, l;
#pragma unroll
    for (int j = 0; j < 8; ++j) {
        float w = -2.0f * src[j];
        _Float16 hh = (_Float16)w;                     // RNE
        h[j] = hh;
        l[j] = (_Float16)((w - (float)hh) * SCALE_LO); // residual, scaled 2^11
    }
    size_t base_h = ((size_t)(t * 2 + 0) * 4 + s) * 512 + (size_t)lane * 8;
    size_t base_l = ((size_t)(t * 2 + 1) * 4 + s) * 512 + (size_t)lane * 8;
    *(half8*)(cbf + base_h) = h;
    *(half8*)(cbf + base_l) = l;
}

// ---- pre-kernel 2: c2[c] = ||c||^2 in double (deterministic)
__global__ void c2_kernel(const float* __restrict__ cb, float* __restrict__ c2) {
    int c = blockIdx.x * 256 + threadIdx.x;
    if (c >= K_CENT) return;
    const float4* row = (const float4*)(cb + (size_t)c * W_DIM);
    double s = 0.0;
#pragma unroll
    for (int j = 0; j < W_DIM / 4; ++j) {
        float4 v = row[j];
        s += (double)v.x * v.x + (double)v.y * v.y + (double)v.z * v.z + (double)v.w * v.w;
    }
    c2[c] = (float)s;
}

// One chunk of 32 centroids vs both 32-point tiles. CURH/CURL were prefetched;
// prefetch NXTH/NXTL for chunk t+1. All register indices compile-time.
#define CHUNK_BODY(T, CURH, CURL, NXTH, NXTL)                                      \
    {                                                                              \
        int t_ = (T);                                                              \
        if (t_ < 15) {                                                             \
            const _Float16* nb = cbf + (size_t)(t_ + 1) * 4096 + (size_t)lane * 8; \
            NXTH[0] = *(const half8*)(nb + 0 * 512);                               \
            NXTH[1] = *(const half8*)(nb + 1 * 512);                               \
            NXTH[2] = *(const half8*)(nb + 2 * 512);                               \
            NXTH[3] = *(const half8*)(nb + 3 * 512);                               \
            NXTL[0] = *(const half8*)(nb + 2048 + 0 * 512);                        \
            NXTL[1] = *(const half8*)(nb + 2048 + 1 * 512);                        \
            NXTL[2] = *(const half8*)(nb + 2048 + 2 * 512);                        \
            NXTL[3] = *(const half8*)(nb + 2048 + 3 * 512);                        \
        }                                                                          \
        float4 q0 = *(const float4*)&c2s[t_ * 32 + half * 4 + 0];                  \
        float4 q1 = *(const float4*)&c2s[t_ * 32 + half * 4 + 8];                  \
        float4 q2 = *(const float4*)&c2s[t_ * 32 + half * 4 + 16];                 \
        float4 q3 = *(const float4*)&c2s[t_ * 32 + half * 4 + 24];                 \
        f32x16 am0, am1, ac0, ac1;                                                 \
        am0[0]=q0.x; am0[1]=q0.y; am0[2]=q0.z; am0[3]=q0.w;                        \
        am0[4]=q1.x; am0[5]=q1.y; am0[6]=q1.z; am0[7]=q1.w;                        \
        am0[8]=q2.x; am0[9]=q2.y; am0[10]=q2.z; am0[11]=q2.w;                      \
        am0[12]=q3.x; am0[13]=q3.y; am0[14]=q3.z; am0[15]=q3.w;                    \
        am1 = am0;                                                                 \
        _Pragma("unroll")                                                          \
        for (int j = 0; j < 16; ++j) { ac0[j] = 0.f; ac1[j] = 0.f; }               \
        _Pragma("unroll")                                                          \
        for (int s = 0; s < 4; ++s) {                                              \
            am0 = __builtin_amdgcn_mfma_f32_32x32x16_f16(CURH[s], b0h[s], am0, 0, 0, 0); \
            am1 = __builtin_amdgcn_mfma_f32_32x32x16_f16(CURH[s], b1h[s], am1, 0, 0, 0); \
            ac0 = __builtin_amdgcn_mfma_f32_32x32x16_f16(CURL[s], b0h[s], ac0, 0, 0, 0); \
            ac1 = __builtin_amdgcn_mfma_f32_32x32x16_f16(CURL[s], b1h[s], ac1, 0, 0, 0); \
            ac0 = __builtin_amdgcn_mfma_f32_32x32x16_f16(CURH[s], b0l[s], ac0, 0, 0, 0); \
            ac1 = __builtin_amdgcn_mfma_f32_32x32x16_f16(CURH[s], b1l[s], ac1, 0, 0, 0); \
        }                                                                          \
        _Pragma("unroll")                                                          \
        for (int j = 0; j < 16; ++j) {                                             \
            int ci = t_ * 32 + half * 4 + (j >> 2) * 8 + (j & 3);                  \
            float v0 = fmaf(ac0[j], INV_LO, am0[j]);                               \
            if (v0 < bd0) { bd0 = v0; bi0 = ci; }                                  \
            float v1d = fmaf(ac1[j], INV_LO, am1[j]);                              \
            if (v1d < bd1) { bd1 = v1d; bi1 = ci; }                                \
        }                                                                          \
    }

// ---- main kernel: 4 waves/block, each wave an independent 64-point job.
__global__ __launch_bounds__(256, 4)
void kmeans_mfma(const float* __restrict__ X,
                 const _Float16* __restrict__ cbf,
                 const float* __restrict__ c2,
                 float* __restrict__ out_idx,
                 float* __restrict__ out_dist) {
    __shared__ float c2s[K_CENT];
    int tid = threadIdx.x;
    c2s[tid] = c2[tid];
    c2s[tid + 256] = c2[tid + 256];
    __syncthreads();

    int wave = tid >> 6;
    int lane = tid & 63;
    int half = lane >> 5;           // 0/1
    int l31  = lane & 31;
    int kb   = half * 8;

    int job = blockIdx.x * 4 + wave;
    if (job >= N_JOBS) return;

    int  p0 = job * 64 + l31;
    bool v1 = (job * 64 + 32) < N_POINTS;
    int  p1 = v1 ? (p0 + 32) : p0;

    // ---- load + convert both X tiles (B operands): f16 hi + scaled lo
    half8 b0h[4], b0l[4], b1h[4], b1l[4];
    float x20 = 0.f, x21 = 0.f;
#pragma unroll
    for (int s = 0; s < 4; ++s) {
        const float4* xa = (const float4*)(X + (size_t)p0 * W_DIM + s * 16 + kb);
        float4 f0 = xa[0], f1 = xa[1];
        float fa[8] = {f0.x, f0.y, f0.z, f0.w, f1.x, f1.y, f1.z, f1.w};
        const float4* xb = (const float4*)(X + (size_t)p1 * W_DIM + s * 16 + kb);
        float4 g0 = xb[0], g1 = xb[1];
        float fb[8] = {g0.x, g0.y, g0.z, g0.w, g1.x, g1.y, g1.z, g1.w};
#pragma unroll
        for (int j = 0; j < 8; ++j) {
            _Float16 h0 = (_Float16)fa[j];
            b0h[s][j] = h0;
            b0l[s][j] = (_Float16)((fa[j] - (float)h0) * SCALE_LO);
            x20 = fmaf(fa[j], fa[j], x20);
            _Float16 h1 = (_Float16)fb[j];
            b1h[s][j] = h1;
            b1l[s][j] = (_Float16)((fb[j] - (float)h1) * SCALE_LO);
            x21 = fmaf(fb[j], fb[j], x21);
        }
    }
    x20 += __shfl_xor(x20, 32);     // halves hold disjoint dims of same point
    x21 += __shfl_xor(x21, 32);

    float bd0 = 3.4e38f, bd1 = 3.4e38f;
    int   bi0 = 0,       bi1 = 0;

    // A-fragment double buffers as NAMED register sets (no runtime indexing)
    half8 ahA[4], alA[4], ahB[4], alB[4];
    {
        const _Float16* ab = cbf + (size_t)lane * 8;
        ahA[0] = *(const half8*)(ab + 0 * 512);
        ahA[1] = *(const half8*)(ab + 1 * 512);
        ahA[2] = *(const half8*)(ab + 2 * 512);
        ahA[3] = *(const half8*)(ab + 3 * 512);
        alA[0] = *(const half8*)(ab + 2048 + 0 * 512);
        alA[1] = *(const half8*)(ab + 2048 + 1 * 512);
        alA[2] = *(const half8*)(ab + 2048 + 2 * 512);
        alA[3] = *(const half8*)(ab + 2048 + 3 * 512);
    }

#pragma unroll 1
    for (int tt = 0; tt < 8; ++tt) {
        CHUNK_BODY(2 * tt,     ahA, alA, ahB, alB)
        CHUNK_BODY(2 * tt + 1, ahB, alB, ahA, alA)
    }

    // combine the two lane-halves (disjoint centroid rows of the same point)
    {
        float od = __shfl_xor(bd0, 32); int oi = __shfl_xor(bi0, 32);
        if (od < bd0 || (od == bd0 && oi < bi0)) { bd0 = od; bi0 = oi; }
        od = __shfl_xor(bd1, 32); oi = __shfl_xor(bi1, 32);
        if (od < bd1 || (od == bd1 && oi < bi1)) { bd1 = od; bi1 = oi; }
    }

    if (half == 0) {
        out_idx[p0]  = (float)bi0;
        out_dist[p0] = sqrtf(fmaxf(bd0 + x20, 0.f));
        if (v1) {
            out_idx[p1]  = (float)bi1;
            out_dist[p1] = sqrtf(fmaxf(bd1 + x21, 0.f));
        }
    }
}

extern "C" void kernel_launch(void* const* d_in, const int* in_sizes, int n_in,
                              void* d_out, int out_size, void* d_ws, size_t ws_size,
                              hipStream_t stream) {
    const float* X  = (const float*)d_in[0];
    const float* cb = (const float*)d_in[1];
    float* out      = (float*)d_out;

    // workspace: fragment-ordered codebook 128KB | c2 2KB
    _Float16* cbf = (_Float16*)d_ws;
    float*    c2  = (float*)(cbf + (size_t)K_CENT * W_DIM * 2);

    hipLaunchKernelGGL(cvt_kernel, dim3((K_CENT * 8 + 255) / 256), dim3(256), 0, stream, cb, cbf);
    hipLaunchKernelGGL(c2_kernel, dim3((K_CENT + 255) / 256), dim3(256), 0, stream, cb, c2);

    hipLaunchKernelGGL(kmeans_mfma, dim3((N_JOBS + 3) / 4), dim3(256), 0, stream,
                       X, cbf, c2, out, out + N_POINTS);
}

// Round 6
// 120.794 us; speedup vs baseline: 3.6274x; 3.6274x over previous
//
#include <hip/hip_runtime.h>

#define N_POINTS 500000
#define K_CENT   512
#define W_DIM    64
#define N_JOBS   ((N_POINTS + 63) / 64)   // 7813 (last job: tile1 invalid)
#define SCALE_LO 2048.0f                  // 2^11
#define INV_LO   (1.0f / 2048.0f)

typedef _Float16 half8 __attribute__((ext_vector_type(8)));
typedef float    f32x16 __attribute__((ext_vector_type(16)));

// ---- pre-kernel 1: codebook -> fragment-ordered f16 hi/lo planes of w = -2*c.
// Layout: [t:16][plane:2][s:4][lane:64][j:8] -> 8 KB/chunk, 128 KB total.
// A-fragment mapping (mfma_f32_32x32x16_f16, verified R2): lane l holds
// row=l&31, k=(l>>5)*8+j of K-step s  => centroid c = t*32+(l&31),
// dim d = s*16 + (l>>5)*8 + j.
__global__ void cvt_kernel(const float* __restrict__ cb,
                           _Float16* __restrict__ cbf) {
    int id = blockIdx.x * 256 + threadIdx.x;           // 4096 ids
    if (id >= K_CENT * 8) return;
    int c = id >> 3, o = (id & 7) * 8;                 // centroid, dim base
    int t = c >> 5, r = c & 31;
    int s = o >> 4, half = (o >> 3) & 1;
    int lane = half * 32 + r;
    const float* src = cb + (size_t)c * W_DIM + o;
    half8 h, l;
#pragma unroll
    for (int j = 0; j < 8; ++j) {
        float w = -2.0f * src[j];
        _Float16 hh = (_Float16)w;                     // RNE
        h[j] = hh;
        l[j] = (_Float16)((w - (float)hh) * SCALE_LO); // residual, scaled 2^11
    }
    size_t base_h = ((size_t)(t * 2 + 0) * 4 + s) * 512 + (size_t)lane * 8;
    size_t base_l = ((size_t)(t * 2 + 1) * 4 + s) * 512 + (size_t)lane * 8;
    *(half8*)(cbf + base_h) = h;
    *(half8*)(cbf + base_l) = l;
}

// ---- pre-kernel 2: c2[c] = ||c||^2 in double (deterministic)
__global__ void c2_kernel(const float* __restrict__ cb, float* __restrict__ c2) {
    int c = blockIdx.x * 256 + threadIdx.x;
    if (c >= K_CENT) return;
    const float4* row = (const float4*)(cb + (size_t)c * W_DIM);
    double s = 0.0;
#pragma unroll
    for (int j = 0; j < W_DIM / 4; ++j) {
        float4 v = row[j];
        s += (double)v.x * v.x + (double)v.y * v.y + (double)v.z * v.z + (double)v.w * v.w;
    }
    c2[c] = (float)s;
}

// One chunk of 32 centroids vs both 32-point tiles. CURH/CURL were prefetched;
// prefetch NXTH/NXTL for chunk t+1. All register indices compile-time.
#define CHUNK_BODY(T, CURH, CURL, NXTH, NXTL)                                      \
    {                                                                              \
        int t_ = (T);                                                              \
        if (t_ < 15) {                                                             \
            const _Float16* nb = cbf + (size_t)(t_ + 1) * 4096 + (size_t)lane * 8; \
            NXTH[0] = *(const half8*)(nb + 0 * 512);                               \
            NXTH[1] = *(const half8*)(nb + 1 * 512);                               \
            NXTH[2] = *(const half8*)(nb + 2 * 512);                               \
            NXTH[3] = *(const half8*)(nb + 3 * 512);                               \
            NXTL[0] = *(const half8*)(nb + 2048 + 0 * 512);                        \
            NXTL[1] = *(const half8*)(nb + 2048 + 1 * 512);                        \
            NXTL[2] = *(const half8*)(nb + 2048 + 2 * 512);                        \
            NXTL[3] = *(const half8*)(nb + 2048 + 3 * 512);                        \
        }                                                                          \
        float4 q0 = *(const float4*)&c2s[t_ * 32 + half * 4 + 0];                  \
        float4 q1 = *(const float4*)&c2s[t_ * 32 + half * 4 + 8];                  \
        float4 q2 = *(const float4*)&c2s[t_ * 32 + half * 4 + 16];                 \
        float4 q3 = *(const float4*)&c2s[t_ * 32 + half * 4 + 24];                 \
        f32x16 am0, am1, ac0, ac1;                                                 \
        am0[0]=q0.x; am0[1]=q0.y; am0[2]=q0.z; am0[3]=q0.w;                        \
        am0[4]=q1.x; am0[5]=q1.y; am0[6]=q1.z; am0[7]=q1.w;                        \
        am0[8]=q2.x; am0[9]=q2.y; am0[10]=q2.z; am0[11]=q2.w;                      \
        am0[12]=q3.x; am0[13]=q3.y; am0[14]=q3.z; am0[15]=q3.w;                    \
        am1 = am0;                                                                 \
        _Pragma("unroll")                                                          \
        for (int j = 0; j < 16; ++j) { ac0[j] = 0.f; ac1[j] = 0.f; }               \
        _Pragma("unroll")                                                          \
        for (int s = 0; s < 4; ++s) {                                              \
            am0 = __builtin_amdgcn_mfma_f32_32x32x16_f16(CURH[s], b0h[s], am0, 0, 0, 0); \
            am1 = __builtin_amdgcn_mfma_f32_32x32x16_f16(CURH[s], b1h[s], am1, 0, 0, 0); \
            ac0 = __builtin_amdgcn_mfma_f32_32x32x16_f16(CURL[s], b0h[s], ac0, 0, 0, 0); \
            ac1 = __builtin_amdgcn_mfma_f32_32x32x16_f16(CURL[s], b1h[s], ac1, 0, 0, 0); \
            ac0 = __builtin_amdgcn_mfma_f32_32x32x16_f16(CURH[s], b0l[s], ac0, 0, 0, 0); \
            ac1 = __builtin_amdgcn_mfma_f32_32x32x16_f16(CURH[s], b1l[s], ac1, 0, 0, 0); \
        }                                                                          \
        _Pragma("unroll")                                                          \
        for (int j = 0; j < 16; ++j) {                                             \
            int ci = t_ * 32 + half * 4 + (j >> 2) * 8 + (j & 3);                  \
            float v0 = fmaf(ac0[j], INV_LO, am0[j]);                               \
            if (v0 < bd0) { bd0 = v0; bi0 = ci; }                                  \
            float v1d = fmaf(ac1[j], INV_LO, am1[j]);                              \
            if (v1d < bd1) { bd1 = v1d; bi1 = ci; }                                \
        }                                                                          \
    }

// ---- main kernel: 4 waves/block, each wave an independent 64-point job.
// launch_bounds (256,2): VGPR cap 256 -> compiler's natural ~110 alloc, no
// spills; HW occupancy then VGPR-limited at 4 waves/SIMD (16 waves/CU).
__global__ __launch_bounds__(256, 2)
void kmeans_mfma(const float* __restrict__ X,
                 const _Float16* __restrict__ cbf,
                 const float* __restrict__ c2,
                 float* __restrict__ out_idx,
                 float* __restrict__ out_dist) {
    __shared__ float c2s[K_CENT];
    int tid = threadIdx.x;
    c2s[tid] = c2[tid];
    c2s[tid + 256] = c2[tid + 256];
    __syncthreads();

    int wave = tid >> 6;
    int lane = tid & 63;
    int half = lane >> 5;           // 0/1
    int l31  = lane & 31;
    int kb   = half * 8;

    int job = blockIdx.x * 4 + wave;
    if (job >= N_JOBS) return;

    int  p0 = job * 64 + l31;
    bool v1 = (job * 64 + 32) < N_POINTS;
    int  p1 = v1 ? (p0 + 32) : p0;

    // ---- load + convert both X tiles (B operands): f16 hi + scaled lo
    half8 b0h[4], b0l[4], b1h[4], b1l[4];
    float x20 = 0.f, x21 = 0.f;
#pragma unroll
    for (int s = 0; s < 4; ++s) {
        const float4* xa = (const float4*)(X + (size_t)p0 * W_DIM + s * 16 + kb);
        float4 f0 = xa[0], f1 = xa[1];
        float fa[8] = {f0.x, f0.y, f0.z, f0.w, f1.x, f1.y, f1.z, f1.w};
        const float4* xb = (const float4*)(X + (size_t)p1 * W_DIM + s * 16 + kb);
        float4 g0 = xb[0], g1 = xb[1];
        float fb[8] = {g0.x, g0.y, g0.z, g0.w, g1.x, g1.y, g1.z, g1.w};
#pragma unroll
        for (int j = 0; j < 8; ++j) {
            _Float16 h0 = (_Float16)fa[j];
            b0h[s][j] = h0;
            b0l[s][j] = (_Float16)((fa[j] - (float)h0) * SCALE_LO);
            x20 = fmaf(fa[j], fa[j], x20);
            _Float16 h1 = (_Float16)fb[j];
            b1h[s][j] = h1;
            b1l[s][j] = (_Float16)((fb[j] - (float)h1) * SCALE_LO);
            x21 = fmaf(fb[j], fb[j], x21);
        }
    }
    x20 += __shfl_xor(x20, 32);     // halves hold disjoint dims of same point
    x21 += __shfl_xor(x21, 32);

    float bd0 = 3.4e38f, bd1 = 3.4e38f;
    int   bi0 = 0,       bi1 = 0;

    // A-fragment double buffers as NAMED register sets (no runtime indexing)
    half8 ahA[4], alA[4], ahB[4], alB[4];
    {
        const _Float16* ab = cbf + (size_t)lane * 8;
        ahA[0] = *(const half8*)(ab + 0 * 512);
        ahA[1] = *(const half8*)(ab + 1 * 512);
        ahA[2] = *(const half8*)(ab + 2 * 512);
        ahA[3] = *(const half8*)(ab + 3 * 512);
        alA[0] = *(const half8*)(ab + 2048 + 0 * 512);
        alA[1] = *(const half8*)(ab + 2048 + 1 * 512);
        alA[2] = *(const half8*)(ab + 2048 + 2 * 512);
        alA[3] = *(const half8*)(ab + 2048 + 3 * 512);
    }

#pragma unroll 1
    for (int tt = 0; tt < 8; ++tt) {
        CHUNK_BODY(2 * tt,     ahA, alA, ahB, alB)
        CHUNK_BODY(2 * tt + 1, ahB, alB, ahA, alA)
    }

    // combine the two lane-halves (disjoint centroid rows of the same point)
    {
        float od = __shfl_xor(bd0, 32); int oi = __shfl_xor(bi0, 32);
        if (od < bd0 || (od == bd0 && oi < bi0)) { bd0 = od; bi0 = oi; }
        od = __shfl_xor(bd1, 32); oi = __shfl_xor(bi1, 32);
        if (od < bd1 || (od == bd1 && oi < bi1)) { bd1 = od; bi1 = oi; }
    }

    if (half == 0) {
        out_idx[p0]  = (float)bi0;
        out_dist[p0] = sqrtf(fmaxf(bd0 + x20, 0.f));
        if (v1) {
            out_idx[p1]  = (float)bi1;
            out_dist[p1] = sqrtf(fmaxf(bd1 + x21, 0.f));
        }
    }
}

extern "C" void kernel_launch(void* const* d_in, const int* in_sizes, int n_in,
                              void* d_out, int out_size, void* d_ws, size_t ws_size,
                              hipStream_t stream) {
    const float* X  = (const float*)d_in[0];
    const float* cb = (const float*)d_in[1];
    float* out      = (float*)d_out;

    // workspace: fragment-ordered codebook 128KB | c2 2KB
    _Float16* cbf = (_Float16*)d_ws;
    float*    c2  = (float*)(cbf + (size_t)K_CENT * W_DIM * 2);

    hipLaunchKernelGGL(cvt_kernel, dim3((K_CENT * 8 + 255) / 256), dim3(256), 0, stream, cb, cbf);
    hipLaunchKernelGGL(c2_kernel, dim3((K_CENT + 255) / 256), dim3(256), 0, stream, cb, c2);

    hipLaunchKernelGGL(kmeans_mfma, dim3((N_JOBS + 3) / 4), dim3(256), 0, stream,
                       X, cbf, c2, out, out + N_POINTS);
}

// Round 7
// 120.640 us; speedup vs baseline: 3.6320x; 1.0013x over previous
//
#include <hip/hip_runtime.h>

#define N_POINTS 500000
#define K_CENT   512
#define W_DIM    64
#define N_JOBS   ((N_POINTS + 63) / 64)   // 7813 (last job: tile1 invalid)
#define SCALE_LO 2048.0f                  // 2^11
#define INV_LO   (1.0f / 2048.0f)

typedef _Float16 half8 __attribute__((ext_vector_type(8)));
typedef float    f32x16 __attribute__((ext_vector_type(16)));

// ---- pre-kernel 1: codebook -> fragment-ordered f16 hi/lo planes of w = -2*c.
// Layout: [t:16][plane:2][s:4][lane:64][j:8] -> 8 KB/chunk, 128 KB total.
// A-fragment mapping (mfma_f32_32x32x16_f16, verified R2): lane l holds
// row=l&31, k=(l>>5)*8+j of K-step s  => centroid c = t*32+(l&31),
// dim d = s*16 + (l>>5)*8 + j.
__global__ void cvt_kernel(const float* __restrict__ cb,
                           _Float16* __restrict__ cbf) {
    int id = blockIdx.x * 256 + threadIdx.x;           // 4096 ids
    if (id >= K_CENT * 8) return;
    int c = id >> 3, o = (id & 7) * 8;                 // centroid, dim base
    int t = c >> 5, r = c & 31;
    int s = o >> 4, half = (o >> 3) & 1;
    int lane = half * 32 + r;
    const float* src = cb + (size_t)c * W_DIM + o;
    half8 h, l;
#pragma unroll
    for (int j = 0; j < 8; ++j) {
        float w = -2.0f * src[j];
        _Float16 hh = (_Float16)w;                     // RNE
        h[j] = hh;
        l[j] = (_Float16)((w - (float)hh) * SCALE_LO); // residual, scaled 2^11
    }
    size_t base_h = ((size_t)(t * 2 + 0) * 4 + s) * 512 + (size_t)lane * 8;
    size_t base_l = ((size_t)(t * 2 + 1) * 4 + s) * 512 + (size_t)lane * 8;
    *(half8*)(cbf + base_h) = h;
    *(half8*)(cbf + base_l) = l;
}

// ---- pre-kernel 2: c2[c] = ||c||^2 in double (deterministic)
__global__ void c2_kernel(const float* __restrict__ cb, float* __restrict__ c2) {
    int c = blockIdx.x * 256 + threadIdx.x;
    if (c >= K_CENT) return;
    const float4* row = (const float4*)(cb + (size_t)c * W_DIM);
    double s = 0.0;
#pragma unroll
    for (int j = 0; j < W_DIM / 4; ++j) {
        float4 v = row[j];
        s += (double)v.x * v.x + (double)v.y * v.y + (double)v.z * v.z + (double)v.w * v.w;
    }
    c2[c] = (float)s;
}

// Epilogue for one tile: v[j] = am[j] + ac[j]*2^-11 + c2; tree-min (depth 4,
// independent pairs) then descending first-match scan (ci monotone in j, so
// smallest matching j == first-index-wins). fmin returns an input bit-exactly,
// so the == match always exists. q0..q3/half4 are in scope at expansion site.
#define ARGMIN_TILE(AM, AC, BD, BI, T_)                                        \
    {                                                                          \
        float v0  = fmaf(AC[0],  INV_LO, AM[0])  + q0.x;                       \
        float v1  = fmaf(AC[1],  INV_LO, AM[1])  + q0.y;                       \
        float v2  = fmaf(AC[2],  INV_LO, AM[2])  + q0.z;                       \
        float v3  = fmaf(AC[3],  INV_LO, AM[3])  + q0.w;                       \
        float v4  = fmaf(AC[4],  INV_LO, AM[4])  + q1.x;                       \
        float v5  = fmaf(AC[5],  INV_LO, AM[5])  + q1.y;                       \
        float v6  = fmaf(AC[6],  INV_LO, AM[6])  + q1.z;                       \
        float v7  = fmaf(AC[7],  INV_LO, AM[7])  + q1.w;                       \
        float v8  = fmaf(AC[8],  INV_LO, AM[8])  + q2.x;                       \
        float v9  = fmaf(AC[9],  INV_LO, AM[9])  + q2.y;                       \
        float v10 = fmaf(AC[10], INV_LO, AM[10]) + q2.z;                       \
        float v11 = fmaf(AC[11], INV_LO, AM[11]) + q2.w;                       \
        float v12 = fmaf(AC[12], INV_LO, AM[12]) + q3.x;                       \
        float v13 = fmaf(AC[13], INV_LO, AM[13]) + q3.y;                       \
        float v14 = fmaf(AC[14], INV_LO, AM[14]) + q3.z;                       \
        float v15 = fmaf(AC[15], INV_LO, AM[15]) + q3.w;                       \
        float m01 = fminf(v0, v1),   m23 = fminf(v2, v3);                      \
        float m45 = fminf(v4, v5),   m67 = fminf(v6, v7);                      \
        float m89 = fminf(v8, v9),   mab = fminf(v10, v11);                    \
        float mcd = fminf(v12, v13), mef = fminf(v14, v15);                    \
        float n0 = fminf(m01, m23),  n1 = fminf(m45, m67);                     \
        float n2 = fminf(m89, mab),  n3 = fminf(mcd, mef);                     \
        float m  = fminf(fminf(n0, n1), fminf(n2, n3));                        \
        int ji = 15;                                                           \
        ji = (v14 == m) ? 14 : ji; ji = (v13 == m) ? 13 : ji;                  \
        ji = (v12 == m) ? 12 : ji; ji = (v11 == m) ? 11 : ji;                  \
        ji = (v10 == m) ? 10 : ji; ji = (v9  == m) ?  9 : ji;                  \
        ji = (v8  == m) ?  8 : ji; ji = (v7  == m) ?  7 : ji;                  \
        ji = (v6  == m) ?  6 : ji; ji = (v5  == m) ?  5 : ji;                  \
        ji = (v4  == m) ?  4 : ji; ji = (v3  == m) ?  3 : ji;                  \
        ji = (v2  == m) ?  2 : ji; ji = (v1  == m) ?  1 : ji;                  \
        ji = (v0  == m) ?  0 : ji;                                             \
        int ci = (T_) * 32 + half4 + ((ji >> 2) << 3) + (ji & 3);              \
        bool imp = m < BD;                                                     \
        BD = imp ? m : BD;                                                     \
        BI = imp ? ci : BI;                                                    \
    }

// One chunk of 32 centroids vs both 32-point tiles. CURH/CURL were prefetched;
// prefetch NXTH/NXTL for chunk t+1. All register indices compile-time.
// Chains start from the persistent ZERO accumulator (no per-chunk init VALU);
// c2 ds_reads issue at top, consumed only in the epilogue (latency hidden
// under the 24-MFMA block).
#define CHUNK_BODY(T, CURH, CURL, NXTH, NXTL)                                      \
    {                                                                              \
        int t_ = (T);                                                              \
        if (t_ < 15) {                                                             \
            const _Float16* nb = cbf + (size_t)(t_ + 1) * 4096 + (size_t)lane * 8; \
            NXTH[0] = *(const half8*)(nb + 0 * 512);                               \
            NXTH[1] = *(const half8*)(nb + 1 * 512);                               \
            NXTH[2] = *(const half8*)(nb + 2 * 512);                               \
            NXTH[3] = *(const half8*)(nb + 3 * 512);                               \
            NXTL[0] = *(const half8*)(nb + 2048 + 0 * 512);                        \
            NXTL[1] = *(const half8*)(nb + 2048 + 1 * 512);                        \
            NXTL[2] = *(const half8*)(nb + 2048 + 2 * 512);                        \
            NXTL[3] = *(const half8*)(nb + 2048 + 3 * 512);                        \
        }                                                                          \
        float4 q0 = *(const float4*)&c2s[t_ * 32 + half4 + 0];                     \
        float4 q1 = *(const float4*)&c2s[t_ * 32 + half4 + 8];                     \
        float4 q2 = *(const float4*)&c2s[t_ * 32 + half4 + 16];                    \
        float4 q3 = *(const float4*)&c2s[t_ * 32 + half4 + 24];                    \
        f32x16 am0, am1, ac0, ac1;                                                 \
        am0 = __builtin_amdgcn_mfma_f32_32x32x16_f16(CURH[0], b0h[0], zro, 0, 0, 0); \
        am1 = __builtin_amdgcn_mfma_f32_32x32x16_f16(CURH[0], b1h[0], zro, 0, 0, 0); \
        ac0 = __builtin_amdgcn_mfma_f32_32x32x16_f16(CURL[0], b0h[0], zro, 0, 0, 0); \
        ac1 = __builtin_amdgcn_mfma_f32_32x32x16_f16(CURL[0], b1h[0], zro, 0, 0, 0); \
        ac0 = __builtin_amdgcn_mfma_f32_32x32x16_f16(CURH[0], b0l[0], ac0, 0, 0, 0); \
        ac1 = __builtin_amdgcn_mfma_f32_32x32x16_f16(CURH[0], b1l[0], ac1, 0, 0, 0); \
        _Pragma("unroll")                                                          \
        for (int s = 1; s < 4; ++s) {                                              \
            am0 = __builtin_amdgcn_mfma_f32_32x32x16_f16(CURH[s], b0h[s], am0, 0, 0, 0); \
            am1 = __builtin_amdgcn_mfma_f32_32x32x16_f16(CURH[s], b1h[s], am1, 0, 0, 0); \
            ac0 = __builtin_amdgcn_mfma_f32_32x32x16_f16(CURL[s], b0h[s], ac0, 0, 0, 0); \
            ac1 = __builtin_amdgcn_mfma_f32_32x32x16_f16(CURL[s], b1h[s], ac1, 0, 0, 0); \
            ac0 = __builtin_amdgcn_mfma_f32_32x32x16_f16(CURH[s], b0l[s], ac0, 0, 0, 0); \
            ac1 = __builtin_amdgcn_mfma_f32_32x32x16_f16(CURH[s], b1l[s], ac1, 0, 0, 0); \
        }                                                                          \
        ARGMIN_TILE(am0, ac0, bd0, bi0, t_)                                        \
        ARGMIN_TILE(am1, ac1, bd1, bi1, t_)                                        \
    }

// ---- main kernel: 4 waves/block, each wave an independent 64-point job.
// (256,2): VGPR cap 256 -> no spills; unified VGPR+AGPR ~190 -> 2 waves/SIMD.
__global__ __launch_bounds__(256, 2)
void kmeans_mfma(const float* __restrict__ X,
                 const _Float16* __restrict__ cbf,
                 const float* __restrict__ c2,
                 float* __restrict__ out_idx,
                 float* __restrict__ out_dist) {
    __shared__ float c2s[K_CENT];
    int tid = threadIdx.x;
    c2s[tid] = c2[tid];
    c2s[tid + 256] = c2[tid + 256];
    __syncthreads();

    int wave = tid >> 6;
    int lane = tid & 63;
    int half = lane >> 5;           // 0/1
    int l31  = lane & 31;
    int kb   = half * 8;
    int half4 = half * 4;

    int job = blockIdx.x * 4 + wave;
    if (job >= N_JOBS) return;

    int  p0 = job * 64 + l31;
    bool v1ok = (job * 64 + 32) < N_POINTS;
    int  p1 = v1ok ? (p0 + 32) : p0;

    // persistent zero accumulator (C-in for each chain's first MFMA)
    f32x16 zro;
#pragma unroll
    for (int j = 0; j < 16; ++j) zro[j] = 0.f;

    // ---- load + convert both X tiles (B operands): f16 hi + scaled lo
    half8 b0h[4], b0l[4], b1h[4], b1l[4];
    float x20 = 0.f, x21 = 0.f;
#pragma unroll
    for (int s = 0; s < 4; ++s) {
        const float4* xa = (const float4*)(X + (size_t)p0 * W_DIM + s * 16 + kb);
        float4 f0 = xa[0], f1 = xa[1];
        float fa[8] = {f0.x, f0.y, f0.z, f0.w, f1.x, f1.y, f1.z, f1.w};
        const float4* xb = (const float4*)(X + (size_t)p1 * W_DIM + s * 16 + kb);
        float4 g0 = xb[0], g1 = xb[1];
        float fb[8] = {g0.x, g0.y, g0.z, g0.w, g1.x, g1.y, g1.z, g1.w};
#pragma unroll
        for (int j = 0; j < 8; ++j) {
            _Float16 h0 = (_Float16)fa[j];
            b0h[s][j] = h0;
            b0l[s][j] = (_Float16)((fa[j] - (float)h0) * SCALE_LO);
            x20 = fmaf(fa[j], fa[j], x20);
            _Float16 h1 = (_Float16)fb[j];
            b1h[s][j] = h1;
            b1l[s][j] = (_Float16)((fb[j] - (float)h1) * SCALE_LO);
            x21 = fmaf(fb[j], fb[j], x21);
        }
    }
    x20 += __shfl_xor(x20, 32);     // halves hold disjoint dims of same point
    x21 += __shfl_xor(x21, 32);

    float bd0 = 3.4e38f, bd1 = 3.4e38f;
    int   bi0 = 0,       bi1 = 0;

    // A-fragment double buffers as NAMED register sets (no runtime indexing)
    half8 ahA[4], alA[4], ahB[4], alB[4];
    {
        const _Float16* ab = cbf + (size_t)lane * 8;
        ahA[0] = *(const half8*)(ab + 0 * 512);
        ahA[1] = *(const half8*)(ab + 1 * 512);
        ahA[2] = *(const half8*)(ab + 2 * 512);
        ahA[3] = *(const half8*)(ab + 3 * 512);
        alA[0] = *(const half8*)(ab + 2048 + 0 * 512);
        alA[1] = *(const half8*)(ab + 2048 + 1 * 512);
        alA[2] = *(const half8*)(ab + 2048 + 2 * 512);
        alA[3] = *(const half8*)(ab + 2048 + 3 * 512);
    }

#pragma unroll 1
    for (int tt = 0; tt < 8; ++tt) {
        CHUNK_BODY(2 * tt,     ahA, alA, ahB, alB)
        CHUNK_BODY(2 * tt + 1, ahB, alB, ahA, alA)
    }

    // combine the two lane-halves (disjoint centroid rows of the same point)
    {
        float od = __shfl_xor(bd0, 32); int oi = __shfl_xor(bi0, 32);
        if (od < bd0 || (od == bd0 && oi < bi0)) { bd0 = od; bi0 = oi; }
        od = __shfl_xor(bd1, 32); oi = __shfl_xor(bi1, 32);
        if (od < bd1 || (od == bd1 && oi < bi1)) { bd1 = od; bi1 = oi; }
    }

    if (half == 0) {
        out_idx[p0]  = (float)bi0;
        out_dist[p0] = sqrtf(fmaxf(bd0 + x20, 0.f));
        if (v1ok) {
            out_idx[p1]  = (float)bi1;
            out_dist[p1] = sqrtf(fmaxf(bd1 + x21, 0.f));
        }
    }
}

extern "C" void kernel_launch(void* const* d_in, const int* in_sizes, int n_in,
                              void* d_out, int out_size, void* d_ws, size_t ws_size,
                              hipStream_t stream) {
    const float* X  = (const float*)d_in[0];
    const float* cb = (const float*)d_in[1];
    float* out      = (float*)d_out;

    // workspace: fragment-ordered codebook 128KB | c2 2KB
    _Float16* cbf = (_Float16*)d_ws;
    float*    c2  = (float*)(cbf + (size_t)K_CENT * W_DIM * 2);

    hipLaunchKernelGGL(cvt_kernel, dim3((K_CENT * 8 + 255) / 256), dim3(256), 0, stream, cb, cbf);
    hipLaunchKernelGGL(c2_kernel, dim3((K_CENT + 255) / 256), dim3(256), 0, stream, cb, c2);

    hipLaunchKernelGGL(kmeans_mfma, dim3((N_JOBS + 3) / 4), dim3(256), 0, stream,
                       X, cbf, c2, out, out + N_POINTS);
}

// Round 8
// 105.151 us; speedup vs baseline: 4.1670x; 1.1473x over previous
//
#include <hip/hip_runtime.h>

#define N_POINTS 500000
#define K_CENT   512
#define W_DIM    64
#define N_JOBS   ((N_POINTS + 63) / 64)   // 7813 (last job: tile1 invalid)

typedef _Float16 half8 __attribute__((ext_vector_type(8)));
typedef float    f32x16 __attribute__((ext_vector_type(16)));

// ---- pre-kernel 1: codebook -> fragment-ordered f16 hi/lo planes of w = -2*c.
// Layout: [t:16][plane:2][s:4][lane:64][j:8] -> 8 KB/chunk, 128 KB total.
// lo plane stores the UNSCALED residual (w - f16(w)) so hi*hi, lo_w*hi_x and
// hi_w*lo_x can share ONE f32 accumulator (sub-denorm residuals contribute
// <~3e-4 to d2 even if flushed - far below near-tie gaps).
__global__ void cvt_kernel(const float* __restrict__ cb,
                           _Float16* __restrict__ cbf) {
    int id = blockIdx.x * 256 + threadIdx.x;           // 4096 ids
    if (id >= K_CENT * 8) return;
    int c = id >> 3, o = (id & 7) * 8;                 // centroid, dim base
    int t = c >> 5, r = c & 31;
    int s = o >> 4, half = (o >> 3) & 1;
    int lane = half * 32 + r;
    const float* src = cb + (size_t)c * W_DIM + o;
    half8 h, l;
#pragma unroll
    for (int j = 0; j < 8; ++j) {
        float w = -2.0f * src[j];
        _Float16 hh = (_Float16)w;                     // RNE
        h[j] = hh;
        l[j] = (_Float16)(w - (float)hh);              // unscaled residual
    }
    size_t base_h = ((size_t)(t * 2 + 0) * 4 + s) * 512 + (size_t)lane * 8;
    size_t base_l = ((size_t)(t * 2 + 1) * 4 + s) * 512 + (size_t)lane * 8;
    *(half8*)(cbf + base_h) = h;
    *(half8*)(cbf + base_l) = l;
}

// ---- pre-kernel 2: c2[c] = ||c||^2 in double (deterministic)
__global__ void c2_kernel(const float* __restrict__ cb, float* __restrict__ c2) {
    int c = blockIdx.x * 256 + threadIdx.x;
    if (c >= K_CENT) return;
    const float4* row = (const float4*)(cb + (size_t)c * W_DIM);
    double s = 0.0;
#pragma unroll
    for (int j = 0; j < W_DIM / 4; ++j) {
        float4 v = row[j];
        s += (double)v.x * v.x + (double)v.y * v.y + (double)v.z * v.z + (double)v.w * v.w;
    }
    c2[c] = (float)s;
}

// MFMA block for chunk T: 24 MFMAs (2 tiles x 3 planes x 4 K-steps), single
// accumulator per tile, C-in = permuted c2 vector QC (prefetched last chunk).
// Also prefetches A(T+1) into NXT* and q(T+1) into QN. All indices static.
#define MFMA_CHUNK(T, CURH, CURL, NXTH, NXTL, QC, QN, A0, A1)                      \
    {                                                                              \
        int t_ = (T);                                                              \
        if (t_ < 15) {                                                             \
            const _Float16* nb = cbf + (size_t)(t_ + 1) * 4096 + (size_t)lane * 8; \
            NXTH[0] = *(const half8*)(nb + 0 * 512);                               \
            NXTH[1] = *(const half8*)(nb + 1 * 512);                               \
            NXTH[2] = *(const half8*)(nb + 2 * 512);                               \
            NXTH[3] = *(const half8*)(nb + 3 * 512);                               \
            NXTL[0] = *(const half8*)(nb + 2048 + 0 * 512);                        \
            NXTL[1] = *(const half8*)(nb + 2048 + 1 * 512);                        \
            NXTL[2] = *(const half8*)(nb + 2048 + 2 * 512);                        \
            NXTL[3] = *(const half8*)(nb + 2048 + 3 * 512);                        \
            QN = *(const f32x16*)&c2s[(t_ + 1) * 32 + half16];                     \
        }                                                                          \
        A0 = __builtin_amdgcn_mfma_f32_32x32x16_f16(CURH[0], b0h[0], QC, 0, 0, 0); \
        A1 = __builtin_amdgcn_mfma_f32_32x32x16_f16(CURH[0], b1h[0], QC, 0, 0, 0); \
        A0 = __builtin_amdgcn_mfma_f32_32x32x16_f16(CURL[0], b0h[0], A0, 0, 0, 0); \
        A1 = __builtin_amdgcn_mfma_f32_32x32x16_f16(CURL[0], b1h[0], A1, 0, 0, 0); \
        A0 = __builtin_amdgcn_mfma_f32_32x32x16_f16(CURH[0], b0l[0], A0, 0, 0, 0); \
        A1 = __builtin_amdgcn_mfma_f32_32x32x16_f16(CURH[0], b1l[0], A1, 0, 0, 0); \
        _Pragma("unroll")                                                          \
        for (int s = 1; s < 4; ++s) {                                              \
            A0 = __builtin_amdgcn_mfma_f32_32x32x16_f16(CURH[s], b0h[s], A0, 0, 0, 0); \
            A1 = __builtin_amdgcn_mfma_f32_32x32x16_f16(CURH[s], b1h[s], A1, 0, 0, 0); \
            A0 = __builtin_amdgcn_mfma_f32_32x32x16_f16(CURL[s], b0h[s], A0, 0, 0, 0); \
            A1 = __builtin_amdgcn_mfma_f32_32x32x16_f16(CURL[s], b1h[s], A1, 0, 0, 0); \
            A0 = __builtin_amdgcn_mfma_f32_32x32x16_f16(CURH[s], b0l[s], A0, 0, 0, 0); \
            A1 = __builtin_amdgcn_mfma_f32_32x32x16_f16(CURH[s], b1l[s], A1, 0, 0, 0); \
        }                                                                          \
    }

// Argmin for one tile: values already include c2 (via C-in). Tree-min (depth
// 4) + descending first-match scan (ci monotone in ji -> first-index-wins;
// fmin returns an input bit-exactly so the == match exists).
#define ARGMIN_TILE(AM, BD, BI, T_)                                            \
    {                                                                          \
        float m01 = fminf(AM[0], AM[1]),   m23 = fminf(AM[2], AM[3]);          \
        float m45 = fminf(AM[4], AM[5]),   m67 = fminf(AM[6], AM[7]);          \
        float m89 = fminf(AM[8], AM[9]),   mab = fminf(AM[10], AM[11]);        \
        float mcd = fminf(AM[12], AM[13]), mef = fminf(AM[14], AM[15]);        \
        float n0 = fminf(m01, m23),  n1 = fminf(m45, m67);                     \
        float n2 = fminf(m89, mab),  n3 = fminf(mcd, mef);                     \
        float m  = fminf(fminf(n0, n1), fminf(n2, n3));                        \
        int ji = 15;                                                           \
        ji = (AM[14] == m) ? 14 : ji; ji = (AM[13] == m) ? 13 : ji;            \
        ji = (AM[12] == m) ? 12 : ji; ji = (AM[11] == m) ? 11 : ji;            \
        ji = (AM[10] == m) ? 10 : ji; ji = (AM[9]  == m) ?  9 : ji;            \
        ji = (AM[8]  == m) ?  8 : ji; ji = (AM[7]  == m) ?  7 : ji;            \
        ji = (AM[6]  == m) ?  6 : ji; ji = (AM[5]  == m) ?  5 : ji;            \
        ji = (AM[4]  == m) ?  4 : ji; ji = (AM[3]  == m) ?  3 : ji;            \
        ji = (AM[2]  == m) ?  2 : ji; ji = (AM[1]  == m) ?  1 : ji;            \
        ji = (AM[0]  == m) ?  0 : ji;                                          \
        int ci = (T_) * 32 + half4 + ((ji >> 2) << 3) + (ji & 3);              \
        bool imp = m < BD;                                                     \
        BD = imp ? m : BD;                                                     \
        BI = imp ? ci : BI;                                                    \
    }

#define ARGMIN_CHUNK(T, A0, A1)                                                \
    {                                                                          \
        ARGMIN_TILE(A0, bd0, bi0, T)                                           \
        ARGMIN_TILE(A1, bd1, bi1, T)                                           \
    }

// ---- main kernel: 4 waves/block, each wave an independent 64-point job.
// Software pipeline: MFMA(t+1) issued BEFORE argmin(t) (P/Q acc sets) so the
// epilogue VALU executes under the next chunk's 24-MFMA shadow.
__global__ __launch_bounds__(256, 2)
void kmeans_mfma(const float* __restrict__ X,
                 const _Float16* __restrict__ cbf,
                 const float* __restrict__ c2,
                 float* __restrict__ out_idx,
                 float* __restrict__ out_dist) {
    // c2 permuted so each lane's 16 C-in values are contiguous:
    // c2s[t*32 + h*16 + j] = c2[t*32 + h*4 + (j>>2)*8 + (j&3)]
    __shared__ float c2s[K_CENT];
    int tid = threadIdx.x;
    {
        int i = tid;
        int t = i >> 5, h = (i >> 4) & 1, j = i & 15;
        c2s[i] = c2[t * 32 + h * 4 + ((j >> 2) << 3) + (j & 3)];
        i = tid + 256;
        t = i >> 5; h = (i >> 4) & 1; j = i & 15;
        c2s[i] = c2[t * 32 + h * 4 + ((j >> 2) << 3) + (j & 3)];
    }
    __syncthreads();

    int wave = tid >> 6;
    int lane = tid & 63;
    int half = lane >> 5;           // 0/1
    int l31  = lane & 31;
    int kb   = half * 8;
    int half4  = half * 4;
    int half16 = half * 16;

    int job = blockIdx.x * 4 + wave;
    if (job >= N_JOBS) return;

    int  p0 = job * 64 + l31;
    bool v1ok = (job * 64 + 32) < N_POINTS;
    int  p1 = v1ok ? (p0 + 32) : p0;

    // ---- load + convert both X tiles (B operands): f16 hi + unscaled lo
    half8 b0h[4], b0l[4], b1h[4], b1l[4];
    float x20 = 0.f, x21 = 0.f;
#pragma unroll
    for (int s = 0; s < 4; ++s) {
        const float4* xa = (const float4*)(X + (size_t)p0 * W_DIM + s * 16 + kb);
        float4 f0 = xa[0], f1 = xa[1];
        float fa[8] = {f0.x, f0.y, f0.z, f0.w, f1.x, f1.y, f1.z, f1.w};
        const float4* xb = (const float4*)(X + (size_t)p1 * W_DIM + s * 16 + kb);
        float4 g0 = xb[0], g1 = xb[1];
        float fb[8] = {g0.x, g0.y, g0.z, g0.w, g1.x, g1.y, g1.z, g1.w};
#pragma unroll
        for (int j = 0; j < 8; ++j) {
            _Float16 h0 = (_Float16)fa[j];
            b0h[s][j] = h0;
            b0l[s][j] = (_Float16)(fa[j] - (float)h0);
            x20 = fmaf(fa[j], fa[j], x20);
            _Float16 h1 = (_Float16)fb[j];
            b1h[s][j] = h1;
            b1l[s][j] = (_Float16)(fb[j] - (float)h1);
            x21 = fmaf(fb[j], fb[j], x21);
        }
    }
    x20 += __shfl_xor(x20, 32);     // halves hold disjoint dims of same point
    x21 += __shfl_xor(x21, 32);

    float bd0 = 3.4e38f, bd1 = 3.4e38f;
    int   bi0 = 0,       bi1 = 0;

    // A-fragment double buffers + q (C-in) double buffers, all named
    half8 ahA[4], alA[4], ahB[4], alB[4];
    f32x16 qP, qQ, accP0, accP1, accQ0, accQ1;
    {
        const _Float16* ab = cbf + (size_t)lane * 8;
        ahA[0] = *(const half8*)(ab + 0 * 512);
        ahA[1] = *(const half8*)(ab + 1 * 512);
        ahA[2] = *(const half8*)(ab + 2 * 512);
        ahA[3] = *(const half8*)(ab + 3 * 512);
        alA[0] = *(const half8*)(ab + 2048 + 0 * 512);
        alA[1] = *(const half8*)(ab + 2048 + 1 * 512);
        alA[2] = *(const half8*)(ab + 2048 + 2 * 512);
        alA[3] = *(const half8*)(ab + 2048 + 3 * 512);
    }
    qP = *(const f32x16*)&c2s[0 * 32 + half16];   // q(0)

    // chunk 0 -> P (prefetch A(1)->B, q(1)->qQ)
    MFMA_CHUNK(0, ahA, alA, ahB, alB, qP, qQ, accP0, accP1)

#pragma unroll 1
    for (int tt = 0; tt < 7; ++tt) {
        MFMA_CHUNK(2 * tt + 1, ahB, alB, ahA, alA, qQ, qP, accQ0, accQ1)
        ARGMIN_CHUNK(2 * tt, accP0, accP1)
        MFMA_CHUNK(2 * tt + 2, ahA, alA, ahB, alB, qP, qQ, accP0, accP1)
        ARGMIN_CHUNK(2 * tt + 1, accQ0, accQ1)
    }
    MFMA_CHUNK(15, ahB, alB, ahA, alA, qQ, qP, accQ0, accQ1)
    ARGMIN_CHUNK(14, accP0, accP1)
    ARGMIN_CHUNK(15, accQ0, accQ1)

    // combine the two lane-halves (disjoint centroid rows of the same point)
    {
        float od = __shfl_xor(bd0, 32); int oi = __shfl_xor(bi0, 32);
        if (od < bd0 || (od == bd0 && oi < bi0)) { bd0 = od; bi0 = oi; }
        od = __shfl_xor(bd1, 32); oi = __shfl_xor(bi1, 32);
        if (od < bd1 || (od == bd1 && oi < bi1)) { bd1 = od; bi1 = oi; }
    }

    if (half == 0) {
        out_idx[p0]  = (float)bi0;
        out_dist[p0] = sqrtf(fmaxf(bd0 + x20, 0.f));
        if (v1ok) {
            out_idx[p1]  = (float)bi1;
            out_dist[p1] = sqrtf(fmaxf(bd1 + x21, 0.f));
        }
    }
}

extern "C" void kernel_launch(void* const* d_in, const int* in_sizes, int n_in,
                              void* d_out, int out_size, void* d_ws, size_t ws_size,
                              hipStream_t stream) {
    const float* X  = (const float*)d_in[0];
    const float* cb = (const float*)d_in[1];
    float* out      = (float*)d_out;

    // workspace: fragment-ordered codebook 128KB | c2 2KB
    _Float16* cbf = (_Float16*)d_ws;
    float*    c2  = (float*)(cbf + (size_t)K_CENT * W_DIM * 2);

    hipLaunchKernelGGL(cvt_kernel, dim3((K_CENT * 8 + 255) / 256), dim3(256), 0, stream, cb, cbf);
    hipLaunchKernelGGL(c2_kernel, dim3((K_CENT + 255) / 256), dim3(256), 0, stream, cb, c2);

    hipLaunchKernelGGL(kmeans_mfma, dim3((N_JOBS + 3) / 4), dim3(256), 0, stream,
                       X, cbf, c2, out, out + N_POINTS);
}